// Round 2
// baseline (494.675 us; speedup 1.0000x reference)
//
#include <hip/hip_runtime.h>
#include <hip/hip_bf16.h>

typedef __bf16 bf16x8_t __attribute__((ext_vector_type(8)));
typedef __bf16 bf16x4_t __attribute__((ext_vector_type(4)));
typedef float  f32x4_t  __attribute__((ext_vector_type(4)));

#define MFMA_16x16x32_BF16(A, B, C) __builtin_amdgcn_mfma_f32_16x16x32_bf16((A), (B), (C), 0, 0, 0)

static constexpr int B_ = 16;
static constexpr int T_ = 2048;
static constexpr int C_ = 1024;
static constexpr int H_ = 128;
static constexpr long M_ = (long)B_ * T_;   // 32768 rows

// ---------------------------------------------------------------------------
// Projection: {q,k,v} = x @ {Wq,Wk,Wv}.  Inputs fp32, converted inline to bf16.
// blockIdx.y selects the weight. q,k written [M_,H_] bf16; v written TRANSPOSED
// per batch: [B_][H_][T_] bf16. Block = 256 threads (4 waves). Each wave:
// 32 rows (2 m-tiles) x 128 cols (8 n-tiles). W tile staged transposed
// (n-major, stride 40) in LDS so the B-fragment is one ds_read_b128.
// ---------------------------------------------------------------------------
__global__ __launch_bounds__(256) void proj_kernel(
    const float* __restrict__ x,
    const float* __restrict__ Wk,
    const float* __restrict__ Wq,
    const float* __restrict__ Wv,
    __bf16* __restrict__ qo,
    __bf16* __restrict__ ko,
    __bf16* __restrict__ vo)
{
    const int z = blockIdx.y;                       // 0 = q, 1 = k, 2 = v
    const float* __restrict__ W = (z == 0) ? Wq : (z == 1) ? Wk : Wv;

    __shared__ __bf16 Wt[128 * 40];                 // [n][kk], stride 40 (bank-conflict pad)

    const int tid  = threadIdx.x;
    const int lane = tid & 63;
    const int w    = tid >> 6;                      // wave 0..3
    const int m16  = lane & 15;
    const int quad = lane >> 4;
    const int koff = quad * 8;

    const long r0 = (long)blockIdx.x * 128 + w * 32;  // wave's first row

    f32x4_t acc0[8], acc1[8];
    #pragma unroll
    for (int i = 0; i < 8; ++i) { acc0[i] = f32x4_t{0,0,0,0}; acc1[i] = f32x4_t{0,0,0,0}; }

    const int n_st = tid >> 1;   // 0..127: which W column this thread stages
    const int half = tid & 1;    // which 16-wide kk half

    for (int k0 = 0; k0 < C_; k0 += 32) {
        // stage W^T tile: Wt[n][kk] = bf16(W[k0+kk][n])
        #pragma unroll
        for (int i = 0; i < 16; ++i) {
            int kk = half * 16 + i;
            Wt[n_st * 40 + kk] = (__bf16)W[(k0 + kk) * H_ + n_st];
        }
        __syncthreads();

        // A fragments from global fp32 (two float4 = 32B/lane), convert to bf16
        const float* xr0 = &x[(r0 + m16) * C_ + k0 + koff];
        const float* xr1 = &x[(r0 + 16 + m16) * C_ + k0 + koff];
        f32x4_t lo0 = *(const f32x4_t*)xr0, hi0 = *(const f32x4_t*)(xr0 + 4);
        f32x4_t lo1 = *(const f32x4_t*)xr1, hi1 = *(const f32x4_t*)(xr1 + 4);
        bf16x8_t a0, a1;
        #pragma unroll
        for (int j = 0; j < 4; ++j) {
            a0[j] = (__bf16)lo0[j]; a0[4 + j] = (__bf16)hi0[j];
            a1[j] = (__bf16)lo1[j]; a1[4 + j] = (__bf16)hi1[j];
        }

        #pragma unroll
        for (int i = 0; i < 8; ++i) {
            bf16x8_t bfr = *(const bf16x8_t*)&Wt[(i * 16 + m16) * 40 + koff];
            acc0[i] = MFMA_16x16x32_BF16(a0, bfr, acc0[i]);
            acc1[i] = MFMA_16x16x32_BF16(a1, bfr, acc1[i]);
        }
        __syncthreads();   // before next stage overwrites Wt
    }

    // Epilogue. C/D layout: col = lane&15, row = quad*4 + r.
    if (z < 2) {
        __bf16* __restrict__ o = (z == 0) ? qo : ko;
        #pragma unroll
        for (int mt = 0; mt < 2; ++mt) {
            f32x4_t* acc = mt ? acc1 : acc0;
            long rb = r0 + mt * 16 + quad * 4;
            #pragma unroll
            for (int i = 0; i < 8; ++i)
                #pragma unroll
                for (int r = 0; r < 4; ++r)
                    o[(rb + r) * H_ + i * 16 + m16] = (__bf16)acc[i][r];
        }
    } else {
        // v transposed: vo[b][h][t]. Rows rb..rb+3 are 4 consecutive t in one
        // batch (2048 | 128-row blocks) -> one 8B store.
        #pragma unroll
        for (int mt = 0; mt < 2; ++mt) {
            f32x4_t* acc = mt ? acc1 : acc0;
            long rb = r0 + mt * 16 + quad * 4;
            long bb = rb >> 11;          // row / 2048
            long tt = rb & 2047;
            #pragma unroll
            for (int i = 0; i < 8; ++i) {
                bf16x4_t pk;
                #pragma unroll
                for (int r = 0; r < 4; ++r) pk[r] = (__bf16)acc[i][r];
                *(bf16x4_t*)&vo[bb * (H_ * (long)T_) + (i * 16 + m16) * (long)T_ + tt] = pk;
            }
        }
    }
}

// ---------------------------------------------------------------------------
// Flash attention, causal. One wave per (batch, 16-row Q tile).
// K-tiles of 32 columns = two 16x16 S tiles, so PV uses a full K=32 MFMA.
// P converts C-layout -> A-layout via an LDS round trip (fp32, stride 36).
// Output stored fp32.
// ---------------------------------------------------------------------------
__global__ __launch_bounds__(64) void attn_kernel(
    const __bf16* __restrict__ q,   // [B][T][H]
    const __bf16* __restrict__ k,   // [B][T][H]
    const __bf16* __restrict__ vT,  // [B][H][T]
    float* __restrict__ out)        // [B][T][H] fp32
{
    const int b    = blockIdx.y;
    const int q0   = blockIdx.x * 16;
    const int lane = threadIdx.x;
    const int m16  = lane & 15;
    const int quad = lane >> 4;
    const int koff = quad * 8;

    const __bf16* __restrict__ qb = q  + (long)b * T_ * H_;
    const __bf16* __restrict__ kb = k  + (long)b * T_ * H_;
    const __bf16* __restrict__ vb = vT + (long)b * H_ * T_;

    // Q A-fragments for the whole tile (H = 4 k-steps of 32)
    bf16x8_t qa[4];
    #pragma unroll
    for (int s = 0; s < 4; ++s)
        qa[s] = *(const bf16x8_t*)&qb[(q0 + m16) * H_ + s * 32 + koff];

    f32x4_t acc[8];
    #pragma unroll
    for (int i = 0; i < 8; ++i) acc[i] = f32x4_t{0,0,0,0};
    float mrun[4] = {-1e30f, -1e30f, -1e30f, -1e30f};
    float lrun[4] = {0.f, 0.f, 0.f, 0.f};

    __shared__ float P32[16 * 36];

    const float SC = 0.08838834764831845f;   // 1/sqrt(128)

    for (int tk0 = 0; tk0 <= q0 + 15; tk0 += 32) {
        // ---- S = Q K^T for 32 k-columns (two 16-wide tiles) ----
        f32x4_t s0 = f32x4_t{0,0,0,0}, s1 = f32x4_t{0,0,0,0};
        #pragma unroll
        for (int s = 0; s < 4; ++s) {
            bf16x8_t k0f = *(const bf16x8_t*)&kb[(tk0      + m16) * H_ + s * 32 + koff];
            bf16x8_t k1f = *(const bf16x8_t*)&kb[(tk0 + 16 + m16) * H_ + s * 32 + koff];
            s0 = MFMA_16x16x32_BF16(qa[s], k0f, s0);
            s1 = MFMA_16x16x32_BF16(qa[s], k1f, s1);
        }

        // ---- scale + causal mask (C layout: col=lane&15, row=quad*4+r) ----
        float v0[4], v1[4], mx[4];
        #pragma unroll
        for (int r = 0; r < 4; ++r) {
            int qrow = q0 + quad * 4 + r;
            v0[r] = (tk0 + m16      <= qrow) ? s0[r] * SC : -1e30f;
            v1[r] = (tk0 + 16 + m16 <= qrow) ? s1[r] * SC : -1e30f;
            mx[r] = fmaxf(v0[r], v1[r]);
        }
        // row max across the 16 lanes of each quad
        #pragma unroll
        for (int off = 1; off <= 8; off <<= 1)
            #pragma unroll
            for (int r = 0; r < 4; ++r)
                mx[r] = fmaxf(mx[r], __shfl_xor(mx[r], off, 64));

        float al[4], p0[4], p1[4], ps[4];
        #pragma unroll
        for (int r = 0; r < 4; ++r) {
            float mnew = fmaxf(mrun[r], mx[r]);
            al[r] = __expf(mrun[r] - mnew);
            p0[r] = __expf(v0[r] - mnew);
            p1[r] = __expf(v1[r] - mnew);
            mrun[r] = mnew;
            ps[r] = p0[r] + p1[r];
        }
        #pragma unroll
        for (int off = 1; off <= 8; off <<= 1)
            #pragma unroll
            for (int r = 0; r < 4; ++r)
                ps[r] += __shfl_xor(ps[r], off, 64);
        #pragma unroll
        for (int r = 0; r < 4; ++r)
            lrun[r] = lrun[r] * al[r] + ps[r];

        // rescale accumulator
        #pragma unroll
        for (int i = 0; i < 8; ++i)
            #pragma unroll
            for (int r = 0; r < 4; ++r)
                acc[i][r] *= al[r];

        // ---- P: C-layout -> A-layout through LDS ----
        __syncthreads();
        #pragma unroll
        for (int r = 0; r < 4; ++r) {
            P32[(quad * 4 + r) * 36 + m16]      = p0[r];
            P32[(quad * 4 + r) * 36 + 16 + m16] = p1[r];
        }
        __syncthreads();
        bf16x8_t pa;
        #pragma unroll
        for (int j = 0; j < 8; ++j)
            pa[j] = (__bf16)P32[m16 * 36 + koff + j];

        // ---- O += P V : 8 h-tiles, B-frag contiguous from transposed V ----
        #pragma unroll
        for (int i = 0; i < 8; ++i) {
            bf16x8_t vv = *(const bf16x8_t*)&vb[(i * 16 + m16) * (long)T_ + tk0 + koff];
            acc[i] = MFMA_16x16x32_BF16(pa, vv, acc[i]);
        }
    }

    // ---- epilogue: divide by softmax denom, store fp32 ----
    float* __restrict__ ob = out + (long)b * T_ * H_;
    #pragma unroll
    for (int i = 0; i < 8; ++i)
        #pragma unroll
        for (int r = 0; r < 4; ++r)
            ob[(q0 + quad * 4 + r) * H_ + i * 16 + m16] = acc[i][r] / lrun[r];
}

// ---------------------------------------------------------------------------
extern "C" void kernel_launch(void* const* d_in, const int* in_sizes, int n_in,
                              void* d_out, int out_size, void* d_ws, size_t ws_size,
                              hipStream_t stream)
{
    // setup_inputs order: x, Wk, Wq, Wv — all float32 per the reference
    const float* x  = (const float*)d_in[0];
    const float* Wk = (const float*)d_in[1];
    const float* Wq = (const float*)d_in[2];
    const float* Wv = (const float*)d_in[3];

    // workspace: q [M,H] bf16, k [M,H] bf16, vT [B][H][T] bf16  (24 MB total)
    __bf16* qws = (__bf16*)d_ws;
    __bf16* kws = qws + M_ * H_;
    __bf16* vws = kws + M_ * H_;
    float*  out = (float*)d_out;

    proj_kernel<<<dim3((int)(M_ / 128), 3), 256, 0, stream>>>(x, Wk, Wq, Wv, qws, kws, vws);
    attn_kernel<<<dim3(T_ / 16, B_), 64, 0, stream>>>(qws, kws, vws, out);
}